// Round 13
// baseline (126.898 us; speedup 1.0000x reference)
//
#include <hip/hip_runtime.h>
#include <hip/hip_bf16.h>

// ---------------------------------------------------------------------------
// MultiHeadedMaskedSelfAttention (B=2,T=2048,C=768,H=12,D=64).
// I/O: float32. Compute: bf16 MFMA with hi/lo compensation on the
// softmax-critical path, plain bf16 elsewhere.
// attn_fwd v12 = v11 (verified 56.0us) + softmax VALU cuts:
//   - exp2 domain: Q pre-scaled by 8*log2(e)=11.5415603 in qkv epilogue;
//     softmax uses native exp2 (v_exp_f32 IS 2^x) - no per-elem muls.
//   - T13 defer-max: skip rescale when __all(mx <= mrow+8); P <= 2^8.
//   - T5 s_setprio(1) around S-phase and PV MFMA clusters.
// Structure (balanced triples, V single-buffer + counted vmcnt, swizzled
// staging, fused V-transpose in qkv) unchanged from v11.
// ---------------------------------------------------------------------------

typedef float f32x4 __attribute__((ext_vector_type(4)));
typedef short s16x8 __attribute__((ext_vector_type(8)));

#define MFMA(a, b, c) __builtin_amdgcn_mfma_f32_16x16x32_bf16((a), (b), (c), 0, 0, 0)

constexpr int Bb = 2, Tt = 2048, Cc = 768, Hh = 12, Dd = 64;
constexpr int Mm = Bb * Tt;   // 4096
constexpr int BH = Bb * Hh;   // 24

__device__ __forceinline__ void gload16(const void* g, void* l) {
  __builtin_amdgcn_global_load_lds((const __attribute__((address_space(1))) void*)g,
                                   (__attribute__((address_space(3))) void*)l, 16, 0, 0);
}

__device__ __forceinline__ short f2bfbits(float f) {
  __hip_bfloat16 h = __float2bfloat16(f);
  return __builtin_bit_cast(short, h);
}
__device__ __forceinline__ float bf2f(short s) {
  __hip_bfloat16 h = __builtin_bit_cast(__hip_bfloat16, s);
  return __bfloat162float(h);
}
__device__ __forceinline__ unsigned int packbf2(float a, float b) {
  return (unsigned int)(unsigned short)f2bfbits(a) |
         ((unsigned int)(unsigned short)f2bfbits(b) << 16);
}

// ---------------------------------------------------------------------------
// prep_all: blocks 0..1535 = prep_x (f32 -> bf16 hi/lo, 8 elts/thr);
// blocks 1536..2111 = prep_w (transpose + hi/lo split, 64x64 tiles).
// ---------------------------------------------------------------------------
__global__ __launch_bounds__(256) void prep_all(
    const float* __restrict__ x,
    const float* __restrict__ s0, const float* __restrict__ s1,
    const float* __restrict__ s2, const float* __restrict__ s3,
    __hip_bfloat16* __restrict__ xhi, __hip_bfloat16* __restrict__ xlo,
    __hip_bfloat16* __restrict__ h0, __hip_bfloat16* __restrict__ l0,
    __hip_bfloat16* __restrict__ h1, __hip_bfloat16* __restrict__ l1,
    __hip_bfloat16* __restrict__ h2, __hip_bfloat16* __restrict__ h3) {
  __shared__ float tile[64][65];
  const int bid = blockIdx.x;
  if (bid < 1536) {
    const size_t i = ((size_t)bid * 256 + threadIdx.x) * 8;
    float4 a = *reinterpret_cast<const float4*>(x + i);
    float4 b = *reinterpret_cast<const float4*>(x + i + 4);
    float v[8] = {a.x, a.y, a.z, a.w, b.x, b.y, b.z, b.w};
    s16x8 hi, lo;
#pragma unroll
    for (int j = 0; j < 8; ++j) {
      short h = f2bfbits(v[j]);
      hi[j] = h;
      lo[j] = f2bfbits(v[j] - bf2f(h));
    }
    *reinterpret_cast<s16x8*>((short*)xhi + i) = hi;
    *reinterpret_cast<s16x8*>((short*)xlo + i) = lo;
    return;
  }
  const int q = bid - 1536;                 // 0..575
  const int z = q / 144, rem = q % 144;
  const int by = rem / 12, bx = rem % 12;
  const float* src;
  __hip_bfloat16 *dh, *dl = nullptr;
  switch (z) {
    case 0: src = s0; dh = h0; dl = l0; break;
    case 1: src = s1; dh = h1; dl = l1; break;
    case 2: src = s2; dh = h2; break;
    default: src = s3; dh = h3; break;
  }
  const int r0 = by * 64, c0 = bx * 64;
  const int tid = threadIdx.x;
  const int rr = tid >> 4, c4 = (tid & 15) * 4;
#pragma unroll
  for (int it = 0; it < 4; ++it) {
    float4 v = *reinterpret_cast<const float4*>(src + (size_t)(r0 + rr + it * 16) * Cc + c0 + c4);
    tile[rr + it * 16][c4 + 0] = v.x;
    tile[rr + it * 16][c4 + 1] = v.y;
    tile[rr + it * 16][c4 + 2] = v.z;
    tile[rr + it * 16][c4 + 3] = v.w;
  }
  __syncthreads();
#pragma unroll
  for (int it = 0; it < 2; ++it) {
    const int id = tid + it * 256;          // 0..511
    const int n = id >> 3, ch = (id & 7) * 8;
    s16x8 hi, lo;
#pragma unroll
    for (int j = 0; j < 8; ++j) {
      float v = tile[ch + j][n];
      short h = f2bfbits(v);
      hi[j] = h;
      lo[j] = f2bfbits(v - bf2f(h));
    }
    *reinterpret_cast<s16x8*>(dh + (size_t)(c0 + n) * Cc + r0 + ch) = hi;
    if (dl) *reinterpret_cast<s16x8*>(dl + (size_t)(c0 + n) * Cc + r0 + ch) = lo;
  }
}

// ---------------------------------------------------------------------------
// 128x128 GEMM cores. A[M,K] * Bt[N,K]^T, K=768, BK=32, 4 waves.
// ---------------------------------------------------------------------------
__device__ __forceinline__ void gemm128_core(const __hip_bfloat16* __restrict__ A,
                                             const __hip_bfloat16* __restrict__ Bt,
                                             int m0, int n0,
                                             short* ldsA, short* ldsB,
                                             f32x4 acc[4][4]) {
  const int tid = threadIdx.x;
  const int w = tid >> 6, l = tid & 63;
  const int wr = w >> 1, wc = w & 1;
  const int srow = l >> 2;
  const int scol = (l & 3) << 3;

  for (int kt = 0; kt < Cc / 32; ++kt) {
    const int kk = kt << 5;
#pragma unroll
    for (int i = 0; i < 2; ++i) {
      const int r = (w << 5) + (i << 4);
      gload16(A + (size_t)(m0 + r + srow) * Cc + kk + scol, ldsA + r * 32);
      gload16(Bt + (size_t)(n0 + r + srow) * Cc + kk + scol, ldsB + r * 32);
    }
    __syncthreads();
    s16x8 af[4], bfr[4];
#pragma unroll
    for (int i = 0; i < 4; ++i) {
      af[i]  = *reinterpret_cast<const s16x8*>(ldsA + ((wr << 6) + (i << 4) + (l & 15)) * 32 + ((l >> 4) << 3));
      bfr[i] = *reinterpret_cast<const s16x8*>(ldsB + ((wc << 6) + (i << 4) + (l & 15)) * 32 + ((l >> 4) << 3));
    }
#pragma unroll
    for (int i = 0; i < 4; ++i)
#pragma unroll
      for (int j = 0; j < 4; ++j)
        acc[i][j] = MFMA(af[i], bfr[j], acc[i][j]);
    __syncthreads();
  }
}

// hi/lo compensated: acc += Ahi*Bhi + (lo ? Ahi*Blo + Alo*Bhi : 0)
__device__ __forceinline__ void gemm128_hilo(
    const __hip_bfloat16* __restrict__ Ahi, const __hip_bfloat16* __restrict__ Alo,
    const __hip_bfloat16* __restrict__ Bhi, const __hip_bfloat16* __restrict__ Blo,
    bool lo, int m0, int n0, short* lds, f32x4 acc[4][4]) {
  short* ldsAh = lds;
  short* ldsAl = lds + 4096;
  short* ldsBh = lds + 8192;
  short* ldsBl = lds + 12288;
  const int tid = threadIdx.x;
  const int w = tid >> 6, l = tid & 63;
  const int wr = w >> 1, wc = w & 1;
  const int srow = l >> 2;
  const int scol = (l & 3) << 3;

  for (int kt = 0; kt < Cc / 32; ++kt) {
    const int kk = kt << 5;
#pragma unroll
    for (int i = 0; i < 2; ++i) {
      const int r = (w << 5) + (i << 4);
      const size_t aoff = (size_t)(m0 + r + srow) * Cc + kk + scol;
      const size_t boff = (size_t)(n0 + r + srow) * Cc + kk + scol;
      gload16(Ahi + aoff, ldsAh + r * 32);
      gload16(Bhi + boff, ldsBh + r * 32);
      if (lo) {
        gload16(Alo + aoff, ldsAl + r * 32);
        gload16(Blo + boff, ldsBl + r * 32);
      }
    }
    __syncthreads();
    s16x8 ah[4], bh[4], al[4], bl[4];
#pragma unroll
    for (int i = 0; i < 4; ++i) {
      const int ao = ((wr << 6) + (i << 4) + (l & 15)) * 32 + ((l >> 4) << 3);
      const int bo = ((wc << 6) + (i << 4) + (l & 15)) * 32 + ((l >> 4) << 3);
      ah[i] = *reinterpret_cast<const s16x8*>(ldsAh + ao);
      bh[i] = *reinterpret_cast<const s16x8*>(ldsBh + bo);
      if (lo) {
        al[i] = *reinterpret_cast<const s16x8*>(ldsAl + ao);
        bl[i] = *reinterpret_cast<const s16x8*>(ldsBl + bo);
      }
    }
#pragma unroll
    for (int i = 0; i < 4; ++i)
#pragma unroll
      for (int j = 0; j < 4; ++j)
        acc[i][j] = MFMA(ah[i], bh[j], acc[i][j]);
    if (lo) {
#pragma unroll
      for (int i = 0; i < 4; ++i)
#pragma unroll
        for (int j = 0; j < 4; ++j) {
          acc[i][j] = MFMA(ah[i], bl[j], acc[i][j]);
          acc[i][j] = MFMA(al[i], bh[j], acc[i][j]);
        }
    }
    __syncthreads();
  }
}

// ---------------------------------------------------------------------------
// QKV projection. grid (32, 6, 3): z=0 -> Q(hi,lo, x8*log2e folded),
// z=1 -> K(hi,lo), z=2 -> V written DIRECTLY TRANSPOSED to VT [BH][D][T].
// ---------------------------------------------------------------------------
__global__ __launch_bounds__(256) void qkv_gemm(
    const __hip_bfloat16* __restrict__ Xhi, const __hip_bfloat16* __restrict__ Xlo,
    const __hip_bfloat16* __restrict__ WqThi, const __hip_bfloat16* __restrict__ WqTlo,
    const __hip_bfloat16* __restrict__ WkThi, const __hip_bfloat16* __restrict__ WkTlo,
    const __hip_bfloat16* __restrict__ WvThi,
    __hip_bfloat16* __restrict__ Qhi, __hip_bfloat16* __restrict__ Qlo,
    __hip_bfloat16* __restrict__ Khi, __hip_bfloat16* __restrict__ Klo,
    __hip_bfloat16* __restrict__ VT) {
  __shared__ __align__(16) short lds[16384];
  const int z = blockIdx.z;
  const bool lo = (z < 2);
  const __hip_bfloat16* Bhi = (z == 0) ? WqThi : (z == 1) ? WkThi : WvThi;
  const __hip_bfloat16* Blo = (z == 0) ? WqTlo : WkTlo;
  const int m0 = blockIdx.x * 128, n0 = blockIdx.y * 128;

  f32x4 acc[4][4];
#pragma unroll
  for (int i = 0; i < 4; ++i)
#pragma unroll
    for (int j = 0; j < 4; ++j) acc[i][j] = f32x4{0.f, 0.f, 0.f, 0.f};

  gemm128_hilo(Xhi, Xlo, Bhi, Blo, lo, m0, n0, lds, acc);

  const int tid = threadIdx.x, w = tid >> 6, l = tid & 63;
  const int wr = w >> 1, wc = w & 1;
  if (z == 2) {
    // V: write transposed, 4 consecutive t per thread -> one uint2 store
#pragma unroll
    for (int i = 0; i < 4; ++i)
#pragma unroll
      for (int j = 0; j < 4; ++j) {
        const int mb = m0 + (wr << 6) + (i << 4) + ((l >> 4) << 2);
        const int n = n0 + (wc << 6) + (j << 4) + (l & 15);
        const int b = mb >> 11, t0 = mb & 2047, h = n >> 6, d = n & 63;
        uint2 pk;
        pk.x = packbf2(acc[i][j][0], acc[i][j][1]);
        pk.y = packbf2(acc[i][j][2], acc[i][j][3]);
        *reinterpret_cast<uint2*>(
            (short*)VT + ((size_t)(b * Hh + h) * Dd + d) * Tt + t0) = pk;
      }
    return;
  }
#pragma unroll
  for (int i = 0; i < 4; ++i) {
#pragma unroll
    for (int j = 0; j < 4; ++j) {
#pragma unroll
      for (int r = 0; r < 4; ++r) {
        const int m = m0 + (wr << 6) + (i << 4) + ((l >> 4) << 2) + r;
        const int n = n0 + (wc << 6) + (j << 4) + (l & 15);
        float v = acc[i][j][r];
        const int b = m >> 11, t = m & 2047, h = n >> 6, d = n & 63;
        const size_t idx = (((size_t)(b * Hh + h)) * Tt + t) * Dd + d;
        if (z == 0) v *= 11.5415603f;   // 8*log2(e): exp2-domain logits
        short hbits = f2bfbits(v);
        short lbits = f2bfbits(v - bf2f(hbits));
        if (z == 0) { ((short*)Qhi)[idx] = hbits; ((short*)Qlo)[idx] = lbits; }
        else        { ((short*)Khi)[idx] = hbits; ((short*)Klo)[idx] = lbits; }
      }
    }
  }
}

// ---------------------------------------------------------------------------
// Output projection: out[M,C] (f32) = O[M,C](bf16) * LT[C,C]^T(bf16). grid(32,6)
// ---------------------------------------------------------------------------
__global__ __launch_bounds__(256) void proj_gemm(
    const __hip_bfloat16* __restrict__ O, const __hip_bfloat16* __restrict__ LT,
    float* __restrict__ out) {
  __shared__ __align__(16) short lds[8192];
  const int m0 = blockIdx.x * 128, n0 = blockIdx.y * 128;
  f32x4 acc[4][4];
#pragma unroll
  for (int i = 0; i < 4; ++i)
#pragma unroll
    for (int j = 0; j < 4; ++j) acc[i][j] = f32x4{0.f, 0.f, 0.f, 0.f};

  gemm128_core(O, LT, m0, n0, lds, lds + 4096, acc);

  const int tid = threadIdx.x, w = tid >> 6, l = tid & 63;
  const int wr = w >> 1, wc = w & 1;
#pragma unroll
  for (int i = 0; i < 4; ++i)
#pragma unroll
    for (int j = 0; j < 4; ++j)
#pragma unroll
      for (int r = 0; r < 4; ++r) {
        const int m = m0 + (wr << 6) + (i << 4) + ((l >> 4) << 2) + r;
        const int n = n0 + (wc << 6) + (j << 4) + (l & 15);
        out[(size_t)m * Cc + n] = acc[i][j][r];
      }
}

// ---------------------------------------------------------------------------
// Causal flash attention v12. grid (768) x 256 threads (4 waves), 3 blocks/CU.
// Structure identical to v11 (balanced triples P0/P1/P2, V single-buffer with
// counted vmcnt, XOR-swizzled staging). Softmax: exp2 domain + defer-max
// (THR=8, P <= 2^8) + setprio around MFMA clusters.
// ---------------------------------------------------------------------------
__global__ __launch_bounds__(256, 3) void attn_fwd(
    const __hip_bfloat16* __restrict__ Qhi, const __hip_bfloat16* __restrict__ Qlo,
    const __hip_bfloat16* __restrict__ Khi, const __hip_bfloat16* __restrict__ Klo,
    const __hip_bfloat16* __restrict__ VT, __hip_bfloat16* __restrict__ O) {
  __shared__ __align__(16) short kvk[2][2][4096];  // [buf][Khi,Klo][64x64]
  __shared__ __align__(16) short kvv[4096];        // V single buffer
  __shared__ __align__(16) short pbuf[4][16 * 72];
  const int i = blockIdx.x;
  const int j = i >> 3;                        // 0..95
  const int m3 = j >> 5;                       // 0..2
  const int bh = (i & 7) * 3 + m3;             // 0..23 (3 heads per XCD)
  const int s_ = j & 31;
  const int h1t[8] = {3, 4, 7, 5, 2, 6, 1, 0};
  const int h2t[8] = {7, 6, 1, 2, 5, 0, 3, 4};
  const int p1t[4] = {2, 3, 1, 0};
  const int p2t[4] = {3, 0, 2, 1};
  const int qblk = (m3 == 0) ? s_
                 : (m3 == 1) ? 4 * h1t[s_ >> 2] + p1t[s_ & 3]
                             : 4 * h2t[s_ >> 2] + p2t[s_ & 3];
  const int b = bh / Hh, h = bh % Hh;
  const int tid = threadIdx.x, w = tid >> 6, l = tid & 63;
  const int lr = l & 15, lg = l >> 4;
  const int q0 = qblk * 64 + w * 16;           // this wave's 16 q-rows
  const size_t hqk = (size_t)bh * Tt * Dd;
  const __hip_bfloat16* qhp = Qhi + hqk;
  const __hip_bfloat16* qlp = Qlo + hqk;
  const __hip_bfloat16* khp = Khi + hqk;
  const __hip_bfloat16* klp = Klo + hqk;
  const __hip_bfloat16* vtp = VT + (size_t)bh * Dd * Tt;
  short* myP = &pbuf[w][0];
  short* obase = (short*)O + (size_t)b * Tt * Cc + h * Dd;

  const int rr = l >> 3;
  const int gg = (l & 7) ^ rr;

  auto stageK = [&](int buf, int k0) {         // 16 issues, 4 per wave
#pragma unroll
    for (int s6 = 0; s6 < 4; ++s6) {
      const int s = w * 4 + s6;                // 0..15
      const int m = s >> 3, i2 = s & 7;
      const int row = i2 * 8 + rr;
      const __hip_bfloat16* src = (m == 0)
          ? khp + (size_t)(k0 + row) * Dd + gg * 8
          : klp + (size_t)(k0 + row) * Dd + gg * 8;
      gload16(src, &kvk[buf][m][i2 * 512]);
    }
  };
  auto stageV = [&](int k0) {                  // 8 issues, 2 per wave
#pragma unroll
    for (int s6 = 0; s6 < 2; ++s6) {
      const int i2 = w * 2 + s6;               // 0..7
      const int row = i2 * 8 + rr;
      gload16(vtp + (size_t)row * Tt + k0 + gg * 8, &kvv[i2 * 512]);
    }
  };

  stageK(0, 0);
  stageV(0);

  // Q fragments (B-operand: col = lr = q), one-time global loads
  s16x8 qh[2], ql[2];
#pragma unroll
  for (int df = 0; df < 2; ++df) {
    const size_t off = (size_t)(q0 + lr) * Dd + df * 32 + lg * 8;
    qh[df] = *reinterpret_cast<const s16x8*>(qhp + off);
    ql[df] = *reinterpret_cast<const s16x8*>(qlp + off);
  }

  f32x4 oacc[4];
#pragma unroll
  for (int df = 0; df < 4; ++df) oacc[df] = f32x4{0.f, 0.f, 0.f, 0.f};
  float mrow = -__builtin_inff(), lrow = 0.f;

  __syncthreads();                             // tile-0 K and V staged

  const int sw = lr & 7;                       // read-side swizzle key
  const int nt = qblk;                         // tiles 0..qblk
  for (int kt = 0; kt <= nt; ++kt) {
    const int cur = kt & 1;
    const int k0 = kt << 6;
    if (kt > 0) stageV(k0);                    // V(kt): issued after barrier
    if (kt < nt) stageK(cur ^ 1, (kt + 1) << 6);   // prefetch next K

    const short* Kh = &kvk[cur][0][0];
    const short* Kl = &kvk[cur][1][0];

    // --- S^T = K Q^T (swapped; hi/lo compensated), K frags from LDS ---
    f32x4 s[4];
#pragma unroll
    for (int kjf = 0; kjf < 4; ++kjf) s[kjf] = f32x4{0.f, 0.f, 0.f, 0.f};
    __builtin_amdgcn_s_setprio(1);
#pragma unroll
    for (int kjf = 0; kjf < 4; ++kjf)
#pragma unroll
      for (int df = 0; df < 2; ++df) {
        const int off = (kjf * 16 + lr) * 64 + (((df * 4 + lg) ^ sw) << 3);
        const s16x8 kh = *reinterpret_cast<const s16x8*>(Kh + off);
        const s16x8 kl = *reinterpret_cast<const s16x8*>(Kl + off);
        s[kjf] = MFMA(kh, qh[df], s[kjf]);
        s[kjf] = MFMA(kl, qh[df], s[kjf]);
        s[kjf] = MFMA(kh, ql[df], s[kjf]);
      }
    __builtin_amdgcn_s_setprio(0);

    // --- in-register online softmax (exp2 domain; scale pre-folded) ---
    const int q = q0 + lr;
    const bool dotmask = (k0 + 63) > q0;
    float mx = -__builtin_inff();
#pragma unroll
    for (int kjf = 0; kjf < 4; ++kjf)
#pragma unroll
      for (int r = 0; r < 4; ++r) {
        float v = s[kjf][r];
        if (dotmask && (k0 + kjf * 16 + lg * 4 + r) > q) v = -__builtin_inff();
        s[kjf][r] = v;
        mx = fmaxf(mx, v);
      }
    mx = fmaxf(mx, __shfl_xor(mx, 16));
    mx = fmaxf(mx, __shfl_xor(mx, 32));
    // T13 defer-max: only rescale when the running max grew by > 8
    if (!__all(mx <= mrow + 8.0f)) {
      const float mnew = fmaxf(mrow, mx);
      const float sc = exp2f(mrow - mnew);
      mrow = mnew;
      lrow *= sc;
#pragma unroll
      for (int df = 0; df < 4; ++df) oacc[df] *= sc;
    }
    float ls = 0.f;
#pragma unroll
    for (int kjf = 0; kjf < 4; ++kjf)
#pragma unroll
      for (int r = 0; r < 4; ++r) {
        const float p = exp2f(s[kjf][r] - mrow);   // bounded by 2^8
        s[kjf][r] = p;
        ls += p;
      }
    ls += __shfl_xor(ls, 16);
    ls += __shfl_xor(ls, 32);
    lrow += ls;

    // --- P -> LDS as [q][k] bf16 (packed b64 writes), wave-private ---
#pragma unroll
    for (int kjf = 0; kjf < 4; ++kjf) {
      uint2 pk;
      pk.x = packbf2(s[kjf][0], s[kjf][1]);
      pk.y = packbf2(s[kjf][2], s[kjf][3]);
      *reinterpret_cast<uint2*>(myP + lr * 72 + kjf * 16 + lg * 4) = pk;
    }

    // --- drain V(kt): per-wave FIFO = [V x2, K(kt+1) x4] -> allow 4 ---
    if (kt < nt) {
      asm volatile("s_waitcnt vmcnt(4)" ::: "memory");
    } else {
      asm volatile("s_waitcnt vmcnt(0)" ::: "memory");
    }
    __builtin_amdgcn_sched_barrier(0);

    // --- O^T += V^T P^T, V frags from single-buffered LDS ---
    __builtin_amdgcn_s_setprio(1);
#pragma unroll
    for (int kf = 0; kf < 2; ++kf) {
      const s16x8 pa = *reinterpret_cast<const s16x8*>(myP + lr * 72 + kf * 32 + lg * 8);
#pragma unroll
      for (int df = 0; df < 4; ++df) {
        const int off = (df * 16 + lr) * 64 + (((kf * 4 + lg) ^ sw) << 3);
        const s16x8 bv = *reinterpret_cast<const s16x8*>(kvv + off);
        oacc[df] = MFMA(bv, pa, oacc[df]);
      }
    }
    __builtin_amdgcn_s_setprio(0);

    __syncthreads();   // all waves done with kvv & kvk[cur]; K prefetch drained
  }

  // --- epilogue: O[b][t=q][h*64+d], packed 8B stores ---
  const float inv = 1.0f / lrow;
  const int t = q0 + lr;
#pragma unroll
  for (int df = 0; df < 4; ++df) {
    uint2 pk;
    pk.x = packbf2(oacc[df][0] * inv, oacc[df][1] * inv);
    pk.y = packbf2(oacc[df][2] * inv, oacc[df][3] * inv);
    *reinterpret_cast<uint2*>(obase + (size_t)t * Cc + df * 16 + lg * 4) = pk;
  }
}

// ---------------------------------------------------------------------------
extern "C" void kernel_launch(void* const* d_in, const int* in_sizes, int n_in,
                              void* d_out, int out_size, void* d_ws, size_t ws_size,
                              hipStream_t stream) {
  (void)in_sizes; (void)n_in; (void)out_size; (void)ws_size;
  const float* x  = (const float*)d_in[0];
  const float* wq = (const float*)d_in[1];
  const float* wk = (const float*)d_in[2];
  const float* wv = (const float*)d_in[3];
  const float* lm = (const float*)d_in[4];
  float* out = (float*)d_out;
  __hip_bfloat16* ws = (__hip_bfloat16*)d_ws;

  const size_t WSZ = (size_t)Cc * Cc;   // 589824
  const size_t TSZ = (size_t)Mm * Cc;   // 3145728
  __hip_bfloat16* WqThi = ws;
  __hip_bfloat16* WqTlo = WqThi + WSZ;
  __hip_bfloat16* WkThi = WqTlo + WSZ;
  __hip_bfloat16* WkTlo = WkThi + WSZ;
  __hip_bfloat16* WvThi = WkTlo + WSZ;
  __hip_bfloat16* LThi  = WvThi + WSZ;
  __hip_bfloat16* Xhi   = LThi + WSZ;
  __hip_bfloat16* Xlo   = Xhi + TSZ;
  __hip_bfloat16* Qhi   = Xlo + TSZ;
  __hip_bfloat16* Qlo   = Qhi + TSZ;
  __hip_bfloat16* Khi   = Qlo + TSZ;
  __hip_bfloat16* Klo   = Khi + TSZ;
  __hip_bfloat16* Vb    = Klo + TSZ;   // unused scratch (kept for layout)
  __hip_bfloat16* VT    = Vb + TSZ;
  __hip_bfloat16* Ob    = Vb;          // O buffer

  prep_all<<<dim3(2112), 256, 0, stream>>>(x, wq, wk, wv, lm, Xhi, Xlo,
                                           WqThi, WqTlo, WkThi, WkTlo, WvThi, LThi);
  qkv_gemm<<<dim3(32, 6, 3), 256, 0, stream>>>(Xhi, Xlo, WqThi, WqTlo, WkThi, WkTlo,
                                               WvThi, Qhi, Qlo, Khi, Klo, VT);
  attn_fwd<<<dim3(768), 256, 0, stream>>>(Qhi, Qlo, Khi, Klo, VT, Ob);
  proj_gemm<<<dim3(32, 6), 256, 0, stream>>>(Ob, LThi, out);
}

// Round 14
// 118.879 us; speedup vs baseline: 1.0675x; 1.0675x over previous
//
#include <hip/hip_runtime.h>
#include <hip/hip_bf16.h>

// ---------------------------------------------------------------------------
// MultiHeadedMaskedSelfAttention (B=2,T=2048,C=768,H=12,D=64).
// I/O: float32. Compute: bf16 MFMA with hi/lo compensation on the
// softmax-critical path, plain bf16 elsewhere.
// attn_fwd v13 = v12 with the two regression sources fixed:
//   - exp2 via RAW v_exp_f32 (__builtin_amdgcn_exp2f), not OCML exp2f
//     (that call is ~10 VALU ops w/ edge-case handling - the r13 regression).
//   - setprio REMOVED (m190: negative in barrier-locked lockstep schedules).
// Kept: exp2-domain Q pre-fold (8*log2e), T13 defer-max (THR=8, P<=2^8),
// balanced triples, V single-buffer + counted vmcnt, swizzled staging,
// fused V-transpose in qkv.
// ---------------------------------------------------------------------------

typedef float f32x4 __attribute__((ext_vector_type(4)));
typedef short s16x8 __attribute__((ext_vector_type(8)));

#define MFMA(a, b, c) __builtin_amdgcn_mfma_f32_16x16x32_bf16((a), (b), (c), 0, 0, 0)

constexpr int Bb = 2, Tt = 2048, Cc = 768, Hh = 12, Dd = 64;
constexpr int Mm = Bb * Tt;   // 4096
constexpr int BH = Bb * Hh;   // 24

__device__ __forceinline__ void gload16(const void* g, void* l) {
  __builtin_amdgcn_global_load_lds((const __attribute__((address_space(1))) void*)g,
                                   (__attribute__((address_space(3))) void*)l, 16, 0, 0);
}

__device__ __forceinline__ short f2bfbits(float f) {
  __hip_bfloat16 h = __float2bfloat16(f);
  return __builtin_bit_cast(short, h);
}
__device__ __forceinline__ float bf2f(short s) {
  __hip_bfloat16 h = __builtin_bit_cast(__hip_bfloat16, s);
  return __bfloat162float(h);
}
__device__ __forceinline__ unsigned int packbf2(float a, float b) {
  return (unsigned int)(unsigned short)f2bfbits(a) |
         ((unsigned int)(unsigned short)f2bfbits(b) << 16);
}

// raw hardware exp2 (v_exp_f32 IS 2^x) - single VALU instruction
#if __has_builtin(__builtin_amdgcn_exp2f)
__device__ __forceinline__ float fexp2(float x) { return __builtin_amdgcn_exp2f(x); }
#else
__device__ __forceinline__ float fexp2(float x) {
  float r;
  asm("v_exp_f32 %0, %1" : "=v"(r) : "v"(x));
  return r;
}
#endif

// ---------------------------------------------------------------------------
// prep_all: blocks 0..1535 = prep_x (f32 -> bf16 hi/lo, 8 elts/thr);
// blocks 1536..2111 = prep_w (transpose + hi/lo split, 64x64 tiles).
// ---------------------------------------------------------------------------
__global__ __launch_bounds__(256) void prep_all(
    const float* __restrict__ x,
    const float* __restrict__ s0, const float* __restrict__ s1,
    const float* __restrict__ s2, const float* __restrict__ s3,
    __hip_bfloat16* __restrict__ xhi, __hip_bfloat16* __restrict__ xlo,
    __hip_bfloat16* __restrict__ h0, __hip_bfloat16* __restrict__ l0,
    __hip_bfloat16* __restrict__ h1, __hip_bfloat16* __restrict__ l1,
    __hip_bfloat16* __restrict__ h2, __hip_bfloat16* __restrict__ h3) {
  __shared__ float tile[64][65];
  const int bid = blockIdx.x;
  if (bid < 1536) {
    const size_t i = ((size_t)bid * 256 + threadIdx.x) * 8;
    float4 a = *reinterpret_cast<const float4*>(x + i);
    float4 b = *reinterpret_cast<const float4*>(x + i + 4);
    float v[8] = {a.x, a.y, a.z, a.w, b.x, b.y, b.z, b.w};
    s16x8 hi, lo;
#pragma unroll
    for (int j = 0; j < 8; ++j) {
      short h = f2bfbits(v[j]);
      hi[j] = h;
      lo[j] = f2bfbits(v[j] - bf2f(h));
    }
    *reinterpret_cast<s16x8*>((short*)xhi + i) = hi;
    *reinterpret_cast<s16x8*>((short*)xlo + i) = lo;
    return;
  }
  const int q = bid - 1536;                 // 0..575
  const int z = q / 144, rem = q % 144;
  const int by = rem / 12, bx = rem % 12;
  const float* src;
  __hip_bfloat16 *dh, *dl = nullptr;
  switch (z) {
    case 0: src = s0; dh = h0; dl = l0; break;
    case 1: src = s1; dh = h1; dl = l1; break;
    case 2: src = s2; dh = h2; break;
    default: src = s3; dh = h3; break;
  }
  const int r0 = by * 64, c0 = bx * 64;
  const int tid = threadIdx.x;
  const int rr = tid >> 4, c4 = (tid & 15) * 4;
#pragma unroll
  for (int it = 0; it < 4; ++it) {
    float4 v = *reinterpret_cast<const float4*>(src + (size_t)(r0 + rr + it * 16) * Cc + c0 + c4);
    tile[rr + it * 16][c4 + 0] = v.x;
    tile[rr + it * 16][c4 + 1] = v.y;
    tile[rr + it * 16][c4 + 2] = v.z;
    tile[rr + it * 16][c4 + 3] = v.w;
  }
  __syncthreads();
#pragma unroll
  for (int it = 0; it < 2; ++it) {
    const int id = tid + it * 256;          // 0..511
    const int n = id >> 3, ch = (id & 7) * 8;
    s16x8 hi, lo;
#pragma unroll
    for (int j = 0; j < 8; ++j) {
      float v = tile[ch + j][n];
      short h = f2bfbits(v);
      hi[j] = h;
      lo[j] = f2bfbits(v - bf2f(h));
    }
    *reinterpret_cast<s16x8*>(dh + (size_t)(c0 + n) * Cc + r0 + ch) = hi;
    if (dl) *reinterpret_cast<s16x8*>(dl + (size_t)(c0 + n) * Cc + r0 + ch) = lo;
  }
}

// ---------------------------------------------------------------------------
// 128x128 GEMM cores. A[M,K] * Bt[N,K]^T, K=768, BK=32, 4 waves.
// ---------------------------------------------------------------------------
__device__ __forceinline__ void gemm128_core(const __hip_bfloat16* __restrict__ A,
                                             const __hip_bfloat16* __restrict__ Bt,
                                             int m0, int n0,
                                             short* ldsA, short* ldsB,
                                             f32x4 acc[4][4]) {
  const int tid = threadIdx.x;
  const int w = tid >> 6, l = tid & 63;
  const int wr = w >> 1, wc = w & 1;
  const int srow = l >> 2;
  const int scol = (l & 3) << 3;

  for (int kt = 0; kt < Cc / 32; ++kt) {
    const int kk = kt << 5;
#pragma unroll
    for (int i = 0; i < 2; ++i) {
      const int r = (w << 5) + (i << 4);
      gload16(A + (size_t)(m0 + r + srow) * Cc + kk + scol, ldsA + r * 32);
      gload16(Bt + (size_t)(n0 + r + srow) * Cc + kk + scol, ldsB + r * 32);
    }
    __syncthreads();
    s16x8 af[4], bfr[4];
#pragma unroll
    for (int i = 0; i < 4; ++i) {
      af[i]  = *reinterpret_cast<const s16x8*>(ldsA + ((wr << 6) + (i << 4) + (l & 15)) * 32 + ((l >> 4) << 3));
      bfr[i] = *reinterpret_cast<const s16x8*>(ldsB + ((wc << 6) + (i << 4) + (l & 15)) * 32 + ((l >> 4) << 3));
    }
#pragma unroll
    for (int i = 0; i < 4; ++i)
#pragma unroll
      for (int j = 0; j < 4; ++j)
        acc[i][j] = MFMA(af[i], bfr[j], acc[i][j]);
    __syncthreads();
  }
}

// hi/lo compensated: acc += Ahi*Bhi + (lo ? Ahi*Blo + Alo*Bhi : 0)
__device__ __forceinline__ void gemm128_hilo(
    const __hip_bfloat16* __restrict__ Ahi, const __hip_bfloat16* __restrict__ Alo,
    const __hip_bfloat16* __restrict__ Bhi, const __hip_bfloat16* __restrict__ Blo,
    bool lo, int m0, int n0, short* lds, f32x4 acc[4][4]) {
  short* ldsAh = lds;
  short* ldsAl = lds + 4096;
  short* ldsBh = lds + 8192;
  short* ldsBl = lds + 12288;
  const int tid = threadIdx.x;
  const int w = tid >> 6, l = tid & 63;
  const int wr = w >> 1, wc = w & 1;
  const int srow = l >> 2;
  const int scol = (l & 3) << 3;

  for (int kt = 0; kt < Cc / 32; ++kt) {
    const int kk = kt << 5;
#pragma unroll
    for (int i = 0; i < 2; ++i) {
      const int r = (w << 5) + (i << 4);
      const size_t aoff = (size_t)(m0 + r + srow) * Cc + kk + scol;
      const size_t boff = (size_t)(n0 + r + srow) * Cc + kk + scol;
      gload16(Ahi + aoff, ldsAh + r * 32);
      gload16(Bhi + boff, ldsBh + r * 32);
      if (lo) {
        gload16(Alo + aoff, ldsAl + r * 32);
        gload16(Blo + boff, ldsBl + r * 32);
      }
    }
    __syncthreads();
    s16x8 ah[4], bh[4], al[4], bl[4];
#pragma unroll
    for (int i = 0; i < 4; ++i) {
      const int ao = ((wr << 6) + (i << 4) + (l & 15)) * 32 + ((l >> 4) << 3);
      const int bo = ((wc << 6) + (i << 4) + (l & 15)) * 32 + ((l >> 4) << 3);
      ah[i] = *reinterpret_cast<const s16x8*>(ldsAh + ao);
      bh[i] = *reinterpret_cast<const s16x8*>(ldsBh + bo);
      if (lo) {
        al[i] = *reinterpret_cast<const s16x8*>(ldsAl + ao);
        bl[i] = *reinterpret_cast<const s16x8*>(ldsBl + bo);
      }
    }
#pragma unroll
    for (int i = 0; i < 4; ++i)
#pragma unroll
      for (int j = 0; j < 4; ++j)
        acc[i][j] = MFMA(ah[i], bh[j], acc[i][j]);
    if (lo) {
#pragma unroll
      for (int i = 0; i < 4; ++i)
#pragma unroll
        for (int j = 0; j < 4; ++j) {
          acc[i][j] = MFMA(ah[i], bl[j], acc[i][j]);
          acc[i][j] = MFMA(al[i], bh[j], acc[i][j]);
        }
    }
    __syncthreads();
  }
}

// ---------------------------------------------------------------------------
// QKV projection. grid (32, 6, 3): z=0 -> Q(hi,lo, x8*log2e folded),
// z=1 -> K(hi,lo), z=2 -> V written DIRECTLY TRANSPOSED to VT [BH][D][T].
// ---------------------------------------------------------------------------
__global__ __launch_bounds__(256) void qkv_gemm(
    const __hip_bfloat16* __restrict__ Xhi, const __hip_bfloat16* __restrict__ Xlo,
    const __hip_bfloat16* __restrict__ WqThi, const __hip_bfloat16* __restrict__ WqTlo,
    const __hip_bfloat16* __restrict__ WkThi, const __hip_bfloat16* __restrict__ WkTlo,
    const __hip_bfloat16* __restrict__ WvThi,
    __hip_bfloat16* __restrict__ Qhi, __hip_bfloat16* __restrict__ Qlo,
    __hip_bfloat16* __restrict__ Khi, __hip_bfloat16* __restrict__ Klo,
    __hip_bfloat16* __restrict__ VT) {
  __shared__ __align__(16) short lds[16384];
  const int z = blockIdx.z;
  const bool lo = (z < 2);
  const __hip_bfloat16* Bhi = (z == 0) ? WqThi : (z == 1) ? WkThi : WvThi;
  const __hip_bfloat16* Blo = (z == 0) ? WqTlo : WkTlo;
  const int m0 = blockIdx.x * 128, n0 = blockIdx.y * 128;

  f32x4 acc[4][4];
#pragma unroll
  for (int i = 0; i < 4; ++i)
#pragma unroll
    for (int j = 0; j < 4; ++j) acc[i][j] = f32x4{0.f, 0.f, 0.f, 0.f};

  gemm128_hilo(Xhi, Xlo, Bhi, Blo, lo, m0, n0, lds, acc);

  const int tid = threadIdx.x, w = tid >> 6, l = tid & 63;
  const int wr = w >> 1, wc = w & 1;
  if (z == 2) {
    // V: write transposed, 4 consecutive t per thread -> one uint2 store
#pragma unroll
    for (int i = 0; i < 4; ++i)
#pragma unroll
      for (int j = 0; j < 4; ++j) {
        const int mb = m0 + (wr << 6) + (i << 4) + ((l >> 4) << 2);
        const int n = n0 + (wc << 6) + (j << 4) + (l & 15);
        const int b = mb >> 11, t0 = mb & 2047, h = n >> 6, d = n & 63;
        uint2 pk;
        pk.x = packbf2(acc[i][j][0], acc[i][j][1]);
        pk.y = packbf2(acc[i][j][2], acc[i][j][3]);
        *reinterpret_cast<uint2*>(
            (short*)VT + ((size_t)(b * Hh + h) * Dd + d) * Tt + t0) = pk;
      }
    return;
  }
#pragma unroll
  for (int i = 0; i < 4; ++i) {
#pragma unroll
    for (int j = 0; j < 4; ++j) {
#pragma unroll
      for (int r = 0; r < 4; ++r) {
        const int m = m0 + (wr << 6) + (i << 4) + ((l >> 4) << 2) + r;
        const int n = n0 + (wc << 6) + (j << 4) + (l & 15);
        float v = acc[i][j][r];
        const int b = m >> 11, t = m & 2047, h = n >> 6, d = n & 63;
        const size_t idx = (((size_t)(b * Hh + h)) * Tt + t) * Dd + d;
        if (z == 0) v *= 11.5415603f;   // 8*log2(e): exp2-domain logits
        short hbits = f2bfbits(v);
        short lbits = f2bfbits(v - bf2f(hbits));
        if (z == 0) { ((short*)Qhi)[idx] = hbits; ((short*)Qlo)[idx] = lbits; }
        else        { ((short*)Khi)[idx] = hbits; ((short*)Klo)[idx] = lbits; }
      }
    }
  }
}

// ---------------------------------------------------------------------------
// Output projection: out[M,C] (f32) = O[M,C](bf16) * LT[C,C]^T(bf16). grid(32,6)
// ---------------------------------------------------------------------------
__global__ __launch_bounds__(256) void proj_gemm(
    const __hip_bfloat16* __restrict__ O, const __hip_bfloat16* __restrict__ LT,
    float* __restrict__ out) {
  __shared__ __align__(16) short lds[8192];
  const int m0 = blockIdx.x * 128, n0 = blockIdx.y * 128;
  f32x4 acc[4][4];
#pragma unroll
  for (int i = 0; i < 4; ++i)
#pragma unroll
    for (int j = 0; j < 4; ++j) acc[i][j] = f32x4{0.f, 0.f, 0.f, 0.f};

  gemm128_core(O, LT, m0, n0, lds, lds + 4096, acc);

  const int tid = threadIdx.x, w = tid >> 6, l = tid & 63;
  const int wr = w >> 1, wc = w & 1;
#pragma unroll
  for (int i = 0; i < 4; ++i)
#pragma unroll
    for (int j = 0; j < 4; ++j)
#pragma unroll
      for (int r = 0; r < 4; ++r) {
        const int m = m0 + (wr << 6) + (i << 4) + ((l >> 4) << 2) + r;
        const int n = n0 + (wc << 6) + (j << 4) + (l & 15);
        out[(size_t)m * Cc + n] = acc[i][j][r];
      }
}

// ---------------------------------------------------------------------------
// Causal flash attention v13. grid (768) x 256 threads (4 waves), 3 blocks/CU.
// Structure identical to v11/v12 (balanced triples, V single-buffer with
// counted vmcnt, XOR-swizzled staging). Softmax: exp2 domain with RAW
// v_exp_f32 + defer-max (THR=8, P <= 2^8). No setprio.
// ---------------------------------------------------------------------------
__global__ __launch_bounds__(256, 3) void attn_fwd(
    const __hip_bfloat16* __restrict__ Qhi, const __hip_bfloat16* __restrict__ Qlo,
    const __hip_bfloat16* __restrict__ Khi, const __hip_bfloat16* __restrict__ Klo,
    const __hip_bfloat16* __restrict__ VT, __hip_bfloat16* __restrict__ O) {
  __shared__ __align__(16) short kvk[2][2][4096];  // [buf][Khi,Klo][64x64]
  __shared__ __align__(16) short kvv[4096];        // V single buffer
  __shared__ __align__(16) short pbuf[4][16 * 72];
  const int i = blockIdx.x;
  const int j = i >> 3;                        // 0..95
  const int m3 = j >> 5;                       // 0..2
  const int bh = (i & 7) * 3 + m3;             // 0..23 (3 heads per XCD)
  const int s_ = j & 31;
  const int h1t[8] = {3, 4, 7, 5, 2, 6, 1, 0};
  const int h2t[8] = {7, 6, 1, 2, 5, 0, 3, 4};
  const int p1t[4] = {2, 3, 1, 0};
  const int p2t[4] = {3, 0, 2, 1};
  const int qblk = (m3 == 0) ? s_
                 : (m3 == 1) ? 4 * h1t[s_ >> 2] + p1t[s_ & 3]
                             : 4 * h2t[s_ >> 2] + p2t[s_ & 3];
  const int b = bh / Hh, h = bh % Hh;
  const int tid = threadIdx.x, w = tid >> 6, l = tid & 63;
  const int lr = l & 15, lg = l >> 4;
  const int q0 = qblk * 64 + w * 16;           // this wave's 16 q-rows
  const size_t hqk = (size_t)bh * Tt * Dd;
  const __hip_bfloat16* qhp = Qhi + hqk;
  const __hip_bfloat16* qlp = Qlo + hqk;
  const __hip_bfloat16* khp = Khi + hqk;
  const __hip_bfloat16* klp = Klo + hqk;
  const __hip_bfloat16* vtp = VT + (size_t)bh * Dd * Tt;
  short* myP = &pbuf[w][0];
  short* obase = (short*)O + (size_t)b * Tt * Cc + h * Dd;

  const int rr = l >> 3;
  const int gg = (l & 7) ^ rr;

  auto stageK = [&](int buf, int k0) {         // 16 issues, 4 per wave
#pragma unroll
    for (int s6 = 0; s6 < 4; ++s6) {
      const int s = w * 4 + s6;                // 0..15
      const int m = s >> 3, i2 = s & 7;
      const int row = i2 * 8 + rr;
      const __hip_bfloat16* src = (m == 0)
          ? khp + (size_t)(k0 + row) * Dd + gg * 8
          : klp + (size_t)(k0 + row) * Dd + gg * 8;
      gload16(src, &kvk[buf][m][i2 * 512]);
    }
  };
  auto stageV = [&](int k0) {                  // 8 issues, 2 per wave
#pragma unroll
    for (int s6 = 0; s6 < 2; ++s6) {
      const int i2 = w * 2 + s6;               // 0..7
      const int row = i2 * 8 + rr;
      gload16(vtp + (size_t)row * Tt + k0 + gg * 8, &kvv[i2 * 512]);
    }
  };

  stageK(0, 0);
  stageV(0);

  // Q fragments (B-operand: col = lr = q), one-time global loads
  s16x8 qh[2], ql[2];
#pragma unroll
  for (int df = 0; df < 2; ++df) {
    const size_t off = (size_t)(q0 + lr) * Dd + df * 32 + lg * 8;
    qh[df] = *reinterpret_cast<const s16x8*>(qhp + off);
    ql[df] = *reinterpret_cast<const s16x8*>(qlp + off);
  }

  f32x4 oacc[4];
#pragma unroll
  for (int df = 0; df < 4; ++df) oacc[df] = f32x4{0.f, 0.f, 0.f, 0.f};
  float mrow = -__builtin_inff(), lrow = 0.f;

  __syncthreads();                             // tile-0 K and V staged

  const int sw = lr & 7;                       // read-side swizzle key
  const int nt = qblk;                         // tiles 0..qblk
  for (int kt = 0; kt <= nt; ++kt) {
    const int cur = kt & 1;
    const int k0 = kt << 6;
    if (kt > 0) stageV(k0);                    // V(kt): issued after barrier
    if (kt < nt) stageK(cur ^ 1, (kt + 1) << 6);   // prefetch next K

    const short* Kh = &kvk[cur][0][0];
    const short* Kl = &kvk[cur][1][0];

    // --- S^T = K Q^T (swapped; hi/lo compensated), K frags from LDS ---
    f32x4 s[4];
#pragma unroll
    for (int kjf = 0; kjf < 4; ++kjf) s[kjf] = f32x4{0.f, 0.f, 0.f, 0.f};
#pragma unroll
    for (int kjf = 0; kjf < 4; ++kjf)
#pragma unroll
      for (int df = 0; df < 2; ++df) {
        const int off = (kjf * 16 + lr) * 64 + (((df * 4 + lg) ^ sw) << 3);
        const s16x8 kh = *reinterpret_cast<const s16x8*>(Kh + off);
        const s16x8 kl = *reinterpret_cast<const s16x8*>(Kl + off);
        s[kjf] = MFMA(kh, qh[df], s[kjf]);
        s[kjf] = MFMA(kl, qh[df], s[kjf]);
        s[kjf] = MFMA(kh, ql[df], s[kjf]);
      }

    // --- in-register online softmax (exp2 domain; scale pre-folded) ---
    const int q = q0 + lr;
    const bool dotmask = (k0 + 63) > q0;
    float mx = -__builtin_inff();
#pragma unroll
    for (int kjf = 0; kjf < 4; ++kjf)
#pragma unroll
      for (int r = 0; r < 4; ++r) {
        float v = s[kjf][r];
        if (dotmask && (k0 + kjf * 16 + lg * 4 + r) > q) v = -__builtin_inff();
        s[kjf][r] = v;
        mx = fmaxf(mx, v);
      }
    mx = fmaxf(mx, __shfl_xor(mx, 16));
    mx = fmaxf(mx, __shfl_xor(mx, 32));
    // T13 defer-max: only rescale when the running max grew by > 8
    if (!__all(mx <= mrow + 8.0f)) {
      const float mnew = fmaxf(mrow, mx);
      const float sc = fexp2(mrow - mnew);
      mrow = mnew;
      lrow *= sc;
#pragma unroll
      for (int df = 0; df < 4; ++df) oacc[df] *= sc;
    }
    float ls = 0.f;
#pragma unroll
    for (int kjf = 0; kjf < 4; ++kjf)
#pragma unroll
      for (int r = 0; r < 4; ++r) {
        const float p = fexp2(s[kjf][r] - mrow);   // bounded by 2^8
        s[kjf][r] = p;
        ls += p;
      }
    ls += __shfl_xor(ls, 16);
    ls += __shfl_xor(ls, 32);
    lrow += ls;

    // --- P -> LDS as [q][k] bf16 (packed b64 writes), wave-private ---
#pragma unroll
    for (int kjf = 0; kjf < 4; ++kjf) {
      uint2 pk;
      pk.x = packbf2(s[kjf][0], s[kjf][1]);
      pk.y = packbf2(s[kjf][2], s[kjf][3]);
      *reinterpret_cast<uint2*>(myP + lr * 72 + kjf * 16 + lg * 4) = pk;
    }

    // --- drain V(kt): per-wave FIFO = [V x2, K(kt+1) x4] -> allow 4 ---
    if (kt < nt) {
      asm volatile("s_waitcnt vmcnt(4)" ::: "memory");
    } else {
      asm volatile("s_waitcnt vmcnt(0)" ::: "memory");
    }
    __builtin_amdgcn_sched_barrier(0);

    // --- O^T += V^T P^T, V frags from single-buffered LDS ---
#pragma unroll
    for (int kf = 0; kf < 2; ++kf) {
      const s16x8 pa = *reinterpret_cast<const s16x8*>(myP + lr * 72 + kf * 32 + lg * 8);
#pragma unroll
      for (int df = 0; df < 4; ++df) {
        const int off = (df * 16 + lr) * 64 + (((kf * 4 + lg) ^ sw) << 3);
        const s16x8 bv = *reinterpret_cast<const s16x8*>(kvv + off);
        oacc[df] = MFMA(bv, pa, oacc[df]);
      }
    }

    __syncthreads();   // all waves done with kvv & kvk[cur]; K prefetch drained
  }

  // --- epilogue: O[b][t=q][h*64+d], packed 8B stores ---
  const float inv = 1.0f / lrow;
  const int t = q0 + lr;
#pragma unroll
  for (int df = 0; df < 4; ++df) {
    uint2 pk;
    pk.x = packbf2(oacc[df][0] * inv, oacc[df][1] * inv);
    pk.y = packbf2(oacc[df][2] * inv, oacc[df][3] * inv);
    *reinterpret_cast<uint2*>(obase + (size_t)t * Cc + df * 16 + lg * 4) = pk;
  }
}

// ---------------------------------------------------------------------------
extern "C" void kernel_launch(void* const* d_in, const int* in_sizes, int n_in,
                              void* d_out, int out_size, void* d_ws, size_t ws_size,
                              hipStream_t stream) {
  (void)in_sizes; (void)n_in; (void)out_size; (void)ws_size;
  const float* x  = (const float*)d_in[0];
  const float* wq = (const float*)d_in[1];
  const float* wk = (const float*)d_in[2];
  const float* wv = (const float*)d_in[3];
  const float* lm = (const float*)d_in[4];
  float* out = (float*)d_out;
  __hip_bfloat16* ws = (__hip_bfloat16*)d_ws;

  const size_t WSZ = (size_t)Cc * Cc;   // 589824
  const size_t TSZ = (size_t)Mm * Cc;   // 3145728
  __hip_bfloat16* WqThi = ws;
  __hip_bfloat16* WqTlo = WqThi + WSZ;
  __hip_bfloat16* WkThi = WqTlo + WSZ;
  __hip_bfloat16* WkTlo = WkThi + WSZ;
  __hip_bfloat16* WvThi = WkTlo + WSZ;
  __hip_bfloat16* LThi  = WvThi + WSZ;
  __hip_bfloat16* Xhi   = LThi + WSZ;
  __hip_bfloat16* Xlo   = Xhi + TSZ;
  __hip_bfloat16* Qhi   = Xlo + TSZ;
  __hip_bfloat16* Qlo   = Qhi + TSZ;
  __hip_bfloat16* Khi   = Qlo + TSZ;
  __hip_bfloat16* Klo   = Khi + TSZ;
  __hip_bfloat16* Vb    = Klo + TSZ;   // unused scratch (kept for layout)
  __hip_bfloat16* VT    = Vb + TSZ;
  __hip_bfloat16* Ob    = Vb;          // O buffer

  prep_all<<<dim3(2112), 256, 0, stream>>>(x, wq, wk, wv, lm, Xhi, Xlo,
                                           WqThi, WqTlo, WkThi, WkTlo, WvThi, LThi);
  qkv_gemm<<<dim3(32, 6, 3), 256, 0, stream>>>(Xhi, Xlo, WqThi, WqTlo, WkThi, WkTlo,
                                               WvThi, Qhi, Qlo, Khi, Klo, VT);
  attn_fwd<<<dim3(768), 256, 0, stream>>>(Qhi, Qlo, Khi, Klo, VT, Ob);
  proj_gemm<<<dim3(32, 6), 256, 0, stream>>>(Ob, LThi, out);
}